// Round 2
// baseline (937.940 us; speedup 1.0000x reference)
//
#include <hip/hip_runtime.h>
#include <stdint.h>

#define N_NODES 100000
#define N_EDGES 1600000
#define NF 128
#define NG 512
#define NC 10

typedef short short8 __attribute__((ext_vector_type(8)));
typedef float f32x4 __attribute__((ext_vector_type(4)));

__device__ __forceinline__ unsigned short f2b(float f) {
    unsigned u = __float_as_uint(f);
    u += 0x7fffu + ((u >> 16) & 1u);
    return (unsigned short)(u >> 16);
}
__device__ __forceinline__ float lo16(unsigned v) { return __uint_as_float(v << 16); }
__device__ __forceinline__ float hi16(unsigned v) { return __uint_as_float(v & 0xffff0000u); }

// ---------------- CSR build ----------------
__global__ void deg_kernel(const int* __restrict__ dst, int* __restrict__ deg) {
    int e = blockIdx.x * blockDim.x + threadIdx.x;
    if (e < N_EDGES) atomicAdd(&deg[dst[e]], 1);
}

__global__ __launch_bounds__(1024) void scan_kernel(const int* __restrict__ deg, int* __restrict__ rowptr) {
    __shared__ int sums[1024];
    const int t = threadIdx.x;
    const int C = (N_NODES + 1023) / 1024;  // 98
    int lo = t * C;
    int hi = min(lo + C, N_NODES);
    int s = 0;
    for (int i = lo; i < hi; ++i) s += deg[i];
    sums[t] = s;
    __syncthreads();
    for (int off = 1; off < 1024; off <<= 1) {
        int v = (t >= off) ? sums[t - off] : 0;
        __syncthreads();
        sums[t] += v;
        __syncthreads();
    }
    int run = sums[t] - s;  // exclusive prefix of this thread's range
    for (int i = lo; i < hi; ++i) { rowptr[i] = run; run += deg[i]; }
    if (hi == N_NODES) rowptr[N_NODES] = run;  // qualifying threads all write the same total
}

__global__ void fill_kernel(const int* __restrict__ src, const int* __restrict__ dst,
                            const int* __restrict__ rowptr, int* __restrict__ cursor,
                            int* __restrict__ eidx) {
    int e = blockIdx.x * blockDim.x + threadIdx.x;
    if (e < N_EDGES) {
        int d = dst[e];
        int p = atomicAdd(&cursor[d], 1);
        eidx[rowptr[d] + p] = src[e];
    }
}

// ---------------- x (f32) -> bf16, 8 elems/thread ----------------
__global__ __launch_bounds__(256) void cvt_kernel(const float* __restrict__ in, unsigned short* __restrict__ out) {
    int i = blockIdx.x * blockDim.x + threadIdx.x;  // one per 8 elements
    const int n8 = N_NODES * NF / 8;
    if (i >= n8) return;
    const float4* ip = (const float4*)in;
    float4 a = ip[2 * i], b = ip[2 * i + 1];
    uint4 o;
    o.x = (unsigned)f2b(a.x) | ((unsigned)f2b(a.y) << 16);
    o.y = (unsigned)f2b(a.z) | ((unsigned)f2b(a.w) << 16);
    o.z = (unsigned)f2b(b.x) | ((unsigned)f2b(b.y) << 16);
    o.w = (unsigned)f2b(b.z) | ((unsigned)f2b(b.w) << 16);
    ((uint4*)out)[i] = o;
}

// ---------------- weight transpose: Bt[layer][n][k] (bf16); k<128 -> Wl[k][n], else Wr[k-128][n]
__global__ void build_bt(const float* __restrict__ w1l, const float* __restrict__ w1r,
                         const float* __restrict__ w2l, const float* __restrict__ w2r,
                         const float* __restrict__ w3l, const float* __restrict__ w3r,
                         unsigned short* __restrict__ Bt) {
    int i = blockIdx.x * blockDim.x + threadIdx.x;
    if (i >= 3 * 128 * 256) return;
    int layer = i / (128 * 256);
    int r = i % (128 * 256);
    int n = r / 256, k = r % 256;
    const float* wl = (layer == 0) ? w1l : (layer == 1) ? w2l : w3l;
    const float* wr = (layer == 0) ? w1r : (layer == 1) ? w2r : w3r;
    float v = (k < 128) ? wl[k * 128 + n] : wr[(k - 128) * 128 + n];
    Bt[i] = f2b(v);
}

// ---------------- mean aggregation over bf16 features: one wave per node, lane owns 2 feats
__global__ __launch_bounds__(256) void agg_kernel(const unsigned short* __restrict__ F,
                                                  const int* __restrict__ rowptr,
                                                  const int* __restrict__ eidx,
                                                  unsigned short* __restrict__ M) {
    int node = blockIdx.x * 4 + (threadIdx.x >> 6);
    if (node >= N_NODES) return;
    int lane = threadIdx.x & 63;
    int beg = rowptr[node], end = rowptr[node + 1];
    const unsigned* Fb = (const unsigned*)F;
    float ax = 0.f, ay = 0.f;
    int t = beg;
    for (; t + 4 <= end; t += 4) {
        int s0 = eidx[t], s1 = eidx[t + 1], s2 = eidx[t + 2], s3 = eidx[t + 3];
        unsigned v0 = Fb[(size_t)s0 * 64 + lane];
        unsigned v1 = Fb[(size_t)s1 * 64 + lane];
        unsigned v2 = Fb[(size_t)s2 * 64 + lane];
        unsigned v3 = Fb[(size_t)s3 * 64 + lane];
        ax += lo16(v0) + lo16(v1) + lo16(v2) + lo16(v3);
        ay += hi16(v0) + hi16(v1) + hi16(v2) + hi16(v3);
    }
    for (; t < end; ++t) {
        unsigned v = Fb[(size_t)eidx[t] * 64 + lane];
        ax += lo16(v);
        ay += hi16(v);
    }
    float inv = 1.0f / (float)max(end - beg, 1);
    unsigned out = (unsigned)f2b(ax * inv) | ((unsigned)f2b(ay * inv) << 16);
    ((unsigned*)M)[(size_t)node * 64 + lane] = out;
}

// ---------------- GEMM: H = relu([mean|feat] @ Bt^T + b), MFMA 16x16x32 bf16, f32 bias ----------------
__global__ __launch_bounds__(256) void gemm_kernel(const unsigned short* __restrict__ Am,
                                                   const unsigned short* __restrict__ Ax,
                                                   const unsigned short* __restrict__ Bt,
                                                   const float* __restrict__ bias,
                                                   unsigned short* __restrict__ Out) {
    const int wave = threadIdx.x >> 6, lane = threadIdx.x & 63;
    const int lrow = lane & 15, quad = lane >> 4;
    const int row0 = blockIdx.x * 64 + wave * 16;
    int arow = row0 + lrow;
    if (arow >= N_NODES) arow = N_NODES - 1;

    f32x4 acc[8];
#pragma unroll
    for (int nt = 0; nt < 8; ++nt) acc[nt] = (f32x4){0.f, 0.f, 0.f, 0.f};

#pragma unroll
    for (int kk = 0; kk < 8; ++kk) {
        const int kb = kk * 32 + quad * 8;
        const unsigned short* ap = (kb < 128) ? (Am + (size_t)arow * 128 + kb)
                                              : (Ax + (size_t)arow * 128 + (kb - 128));
        short8 af = *(const short8*)ap;
#pragma unroll
        for (int nt = 0; nt < 8; ++nt) {
            short8 bf = *(const short8*)(Bt + (size_t)(nt * 16 + lrow) * 256 + kb);
            acc[nt] = __builtin_amdgcn_mfma_f32_16x16x32_bf16(af, bf, acc[nt], 0, 0, 0);
        }
    }

#pragma unroll
    for (int nt = 0; nt < 8; ++nt) {
        int col = nt * 16 + lrow;
        float bc = bias[col];
#pragma unroll
        for (int r = 0; r < 4; ++r) {
            int row = row0 + quad * 4 + r;
            if (row < N_NODES) {
                float v = acc[nt][r] + bc;
                v = fmaxf(v, 0.f);
                Out[(size_t)row * 128 + col] = f2b(v);
            }
        }
    }
}

// ---------------- gate: gate[i] = h[i] . gate_w + gate_b (h bf16, w/b f32) ----------------
__global__ __launch_bounds__(256) void gate_kernel(const unsigned short* __restrict__ h,
                                                   const float* __restrict__ gw,
                                                   const float* __restrict__ gb,
                                                   float* __restrict__ gate) {
    int node = blockIdx.x * 4 + (threadIdx.x >> 6);
    if (node >= N_NODES) return;
    int lane = threadIdx.x & 63;
    unsigned hv = ((const unsigned*)h)[(size_t)node * 64 + lane];
    float w0 = gw[2 * lane], w1 = gw[2 * lane + 1];
    float s = lo16(hv) * w0 + hi16(hv) * w1;
#pragma unroll
    for (int o = 32; o; o >>= 1) s += __shfl_down(s, o);
    if (lane == 0) gate[node] = s + gb[0];
}

// ---------------- graph segment bounds via binary search (batch is sorted) ----------------
__global__ __launch_bounds__(1024) void bounds_kernel(const int* __restrict__ batch, int* __restrict__ gstart) {
    int g = threadIdx.x + blockIdx.x * blockDim.x;
    if (g > NG) return;
    int lo = 0, hi = N_NODES;
    while (lo < hi) {
        int mid = (lo + hi) >> 1;
        if (batch[mid] < g) lo = mid + 1; else hi = mid;
    }
    gstart[g] = lo;
}

// ---------------- fused attention-pool + MLP + log_softmax: one wave per graph ----------------
__global__ __launch_bounds__(256) void pool_mlp_kernel(const unsigned short* __restrict__ h,
                                                       const float* __restrict__ gate,
                                                       const int* __restrict__ gstart,
                                                       const float* __restrict__ l1w,
                                                       const float* __restrict__ l1b,
                                                       const float* __restrict__ l2w,
                                                       const float* __restrict__ l2b,
                                                       float* __restrict__ out) {
    int wv = threadIdx.x >> 6;
    int g = blockIdx.x * 4 + wv;
    int lane = threadIdx.x & 63;
    __shared__ float pooled_s[4][128];
    __shared__ float hid_s[4][128];
    if (g >= NG) return;

    int beg = gstart[g], end = gstart[g + 1];

    // pass 1: max gate
    float m = -INFINITY;
    for (int i = beg + lane; i < end; i += 64) m = fmaxf(m, gate[i]);
#pragma unroll
    for (int o = 32; o; o >>= 1) m = fmaxf(m, __shfl_xor(m, o));
    // pass 2: sum exp
    float s = 0.f;
    for (int i = beg + lane; i < end; i += 64) s += expf(gate[i] - m);
#pragma unroll
    for (int o = 32; o; o >>= 1) s += __shfl_xor(s, o);
    float invs = (s > 0.f) ? 1.0f / s : 0.f;

    // pass 3: weighted feature sum (lane owns feats 2*lane, 2*lane+1)
    float ax = 0.f, ay = 0.f;
    const unsigned* hb = (const unsigned*)h;
    int i = beg;
    for (; i + 2 <= end; i += 2) {
        float w0 = expf(gate[i] - m) * invs;
        float w1 = expf(gate[i + 1] - m) * invs;
        unsigned v0 = hb[(size_t)i * 64 + lane];
        unsigned v1 = hb[(size_t)(i + 1) * 64 + lane];
        ax += w0 * lo16(v0) + w1 * lo16(v1);
        ay += w0 * hi16(v0) + w1 * hi16(v1);
    }
    for (; i < end; ++i) {
        float w = expf(gate[i] - m) * invs;
        unsigned v = hb[(size_t)i * 64 + lane];
        ax += w * lo16(v);
        ay += w * hi16(v);
    }
    pooled_s[wv][2 * lane] = ax;
    pooled_s[wv][2 * lane + 1] = ay;

    // hidden = relu(pooled @ l1w + l1b); lane owns cols lane and lane+64
    float h0 = l1b[lane], h1 = l1b[lane + 64];
    for (int k = 0; k < 128; ++k) {
        float pv = pooled_s[wv][k];
        h0 += pv * l1w[k * 128 + lane];
        h1 += pv * l1w[k * 128 + lane + 64];
    }
    hid_s[wv][lane] = fmaxf(h0, 0.f);
    hid_s[wv][lane + 64] = fmaxf(h1, 0.f);

    // out10 = hidden @ l2w + l2b, then log_softmax
    float o10 = 0.f;
    if (lane < NC) {
        o10 = l2b[lane];
        for (int k = 0; k < 128; ++k) o10 += hid_s[wv][k] * l2w[k * NC + lane];
    }
    float mm = -INFINITY;
#pragma unroll
    for (int j = 0; j < NC; ++j) mm = fmaxf(mm, __shfl(o10, j));
    float ss = 0.f;
#pragma unroll
    for (int j = 0; j < NC; ++j) ss += expf(__shfl(o10, j) - mm);
    float lse = mm + logf(ss);
    if (lane < NC) out[g * NC + lane] = o10 - lse;
}

extern "C" void kernel_launch(void* const* d_in, const int* in_sizes, int n_in,
                              void* d_out, int out_size, void* d_ws, size_t ws_size,
                              hipStream_t stream) {
    const float* x   = (const float*)d_in[0];
    const int* ei    = (const int*)d_in[1];
    const int* batch = (const int*)d_in[2];
    const float* w1l = (const float*)d_in[3];
    const float* b1  = (const float*)d_in[4];
    const float* w1r = (const float*)d_in[5];
    const float* w2l = (const float*)d_in[6];
    const float* b2  = (const float*)d_in[7];
    const float* w2r = (const float*)d_in[8];
    const float* w3l = (const float*)d_in[9];
    const float* b3  = (const float*)d_in[10];
    const float* w3r = (const float*)d_in[11];
    const float* gw  = (const float*)d_in[12];
    const float* gb  = (const float*)d_in[13];
    const float* l1w = (const float*)d_in[14];
    const float* l1b = (const float*)d_in[15];
    const float* l2w = (const float*)d_in[16];
    const float* l2b = (const float*)d_in[17];
    float* out = (float*)d_out;

    const int* src = ei;
    const int* dst = ei + N_EDGES;

    char* base = (char*)d_ws;
    size_t off = 0;
    auto carve = [&](size_t bytes) -> void* {
        void* r = base + off;
        off = (off + bytes + 255) & ~(size_t)255;
        return r;
    };
    int* deg            = (int*)carve((size_t)N_NODES * 4);
    int* rowptr         = (int*)carve((size_t)(N_NODES + 1) * 4);
    int* cursor         = (int*)carve((size_t)N_NODES * 4);
    int* eidx           = (int*)carve((size_t)N_EDGES * 4);
    unsigned short* Bt  = (unsigned short*)carve((size_t)3 * 128 * 256 * 2);
    unsigned short* xb  = (unsigned short*)carve((size_t)N_NODES * NF * 2);
    unsigned short* mn  = (unsigned short*)carve((size_t)N_NODES * NF * 2);
    unsigned short* hA  = (unsigned short*)carve((size_t)N_NODES * NF * 2);
    unsigned short* hB  = (unsigned short*)carve((size_t)N_NODES * NF * 2);
    float* gate         = (float*)carve((size_t)N_NODES * 4);
    int* gstart         = (int*)carve(513 * 4);

    hipMemsetAsync(deg, 0, (size_t)N_NODES * 4, stream);
    hipMemsetAsync(cursor, 0, (size_t)N_NODES * 4, stream);

    const int EB = (N_EDGES + 255) / 256;  // 6250
    deg_kernel<<<EB, 256, 0, stream>>>(dst, deg);
    scan_kernel<<<1, 1024, 0, stream>>>(deg, rowptr);
    fill_kernel<<<EB, 256, 0, stream>>>(src, dst, rowptr, cursor, eidx);
    build_bt<<<(3 * 128 * 256 + 255) / 256, 256, 0, stream>>>(w1l, w1r, w2l, w2r, w3l, w3r, Bt);
    cvt_kernel<<<(N_NODES * NF / 8 + 255) / 256, 256, 0, stream>>>(x, xb);

    const int AGG_B = (N_NODES + 3) / 4;    // 25000
    const int GEMM_B = (N_NODES + 63) / 64; // 1563

    // layer 1
    agg_kernel<<<AGG_B, 256, 0, stream>>>(xb, rowptr, eidx, mn);
    gemm_kernel<<<GEMM_B, 256, 0, stream>>>(mn, xb, Bt, b1, hA);
    // layer 2
    agg_kernel<<<AGG_B, 256, 0, stream>>>(hA, rowptr, eidx, mn);
    gemm_kernel<<<GEMM_B, 256, 0, stream>>>(mn, hA, Bt + 32768, b2, hB);
    // layer 3
    agg_kernel<<<AGG_B, 256, 0, stream>>>(hB, rowptr, eidx, mn);
    gemm_kernel<<<GEMM_B, 256, 0, stream>>>(mn, hB, Bt + 65536, b3, hA);

    gate_kernel<<<AGG_B, 256, 0, stream>>>(hA, gw, gb, gate);
    bounds_kernel<<<1, 1024, 0, stream>>>(batch, gstart);
    pool_mlp_kernel<<<(NG + 3) / 4, 256, 0, stream>>>(hA, gate, gstart, l1w, l1b, l2w, l2b, out);
}

// Round 3
// 742.385 us; speedup vs baseline: 1.2634x; 1.2634x over previous
//
#include <hip/hip_runtime.h>
#include <stdint.h>

#define N_NODES 100000
#define N_EDGES 1600000
#define NF 128
#define NG 512
#define NC 10

#define SCAN_ELEMS 1024  // per block, 4 per thread
#define N_SCAN_BLOCKS ((N_NODES + SCAN_ELEMS - 1) / SCAN_ELEMS)  // 98

typedef short short8 __attribute__((ext_vector_type(8)));
typedef float f32x4 __attribute__((ext_vector_type(4)));

__device__ __forceinline__ unsigned short f2b(float f) {
    unsigned u = __float_as_uint(f);
    u += 0x7fffu + ((u >> 16) & 1u);
    return (unsigned short)(u >> 16);
}
__device__ __forceinline__ float lo16(unsigned v) { return __uint_as_float(v << 16); }
__device__ __forceinline__ float hi16(unsigned v) { return __uint_as_float(v & 0xffff0000u); }

// ---------------- CSR build ----------------
__global__ void deg_kernel(const int* __restrict__ dst, int* __restrict__ deg) {
    int e = blockIdx.x * blockDim.x + threadIdx.x;
    if (e < N_EDGES) atomicAdd(&deg[dst[e]], 1);
}

// --- scan step 1: per-block sums (coalesced int4) ---
__global__ __launch_bounds__(256) void scan_blocksum(const int* __restrict__ deg, int* __restrict__ bsum) {
    __shared__ int red[256];
    const int t = threadIdx.x;
    const int base = blockIdx.x * SCAN_ELEMS + t * 4;
    int s = 0;
    if (base < N_NODES) {  // N_NODES % 4 == 0, so chunk is fully in-range
        int4 v = *(const int4*)(deg + base);
        s = v.x + v.y + v.z + v.w;
    }
    red[t] = s;
    __syncthreads();
    for (int off = 128; off; off >>= 1) {
        if (t < off) red[t] += red[t + off];
        __syncthreads();
    }
    if (t == 0) bsum[blockIdx.x] = red[0];
}

// --- scan step 2: exclusive scan of the 98 block sums (single tiny block) ---
__global__ __launch_bounds__(128) void scan_partials(const int* __restrict__ bsum, int* __restrict__ boff) {
    __shared__ int sh[128];
    const int t = threadIdx.x;
    int v = (t < N_SCAN_BLOCKS) ? bsum[t] : 0;
    sh[t] = v;
    __syncthreads();
    for (int off = 1; off < 128; off <<= 1) {
        int u = (t >= off) ? sh[t - off] : 0;
        __syncthreads();
        sh[t] += u;
        __syncthreads();
    }
    if (t < N_SCAN_BLOCKS) boff[t] = sh[t] - v;  // exclusive prefix
}

// --- scan step 3: full exclusive scan, coalesced int4 in/out ---
__global__ __launch_bounds__(256) void scan_final(const int* __restrict__ deg, const int* __restrict__ boff,
                                                  int* __restrict__ rowptr) {
    __shared__ int warp_s[4];
    const int t = threadIdx.x, lane = t & 63, wv = t >> 6;
    const int base = blockIdx.x * SCAN_ELEMS + t * 4;
    int4 v = {0, 0, 0, 0};
    if (base < N_NODES) v = *(const int4*)(deg + base);
    int s = v.x + v.y + v.z + v.w;
    // wave inclusive scan
    int isc = s;
#pragma unroll
    for (int off = 1; off < 64; off <<= 1) {
        int u = __shfl_up(isc, off);
        if (lane >= off) isc += u;
    }
    if (lane == 63) warp_s[wv] = isc;
    __syncthreads();
    int woff = 0;
    for (int w = 0; w < wv; ++w) woff += warp_s[w];
    int excl = boff[blockIdx.x] + woff + (isc - s);
    if (base < N_NODES) {
        int4 r;
        r.x = excl;
        r.y = excl + v.x;
        r.z = excl + v.x + v.y;
        r.w = excl + v.x + v.y + v.z;
        *(int4*)(rowptr + base) = r;
    }
    if (blockIdx.x == 0 && t == 0) rowptr[N_NODES] = N_EDGES;  // every dst is in range
}

__global__ void fill_kernel(const int* __restrict__ src, const int* __restrict__ dst,
                            const int* __restrict__ rowptr, int* __restrict__ cursor,
                            int* __restrict__ eidx) {
    int e = blockIdx.x * blockDim.x + threadIdx.x;
    if (e < N_EDGES) {
        int d = dst[e];
        int p = atomicAdd(&cursor[d], 1);
        eidx[rowptr[d] + p] = src[e];
    }
}

// ---------------- x (f32) -> bf16, 8 elems/thread ----------------
__global__ __launch_bounds__(256) void cvt_kernel(const float* __restrict__ in, unsigned short* __restrict__ out) {
    int i = blockIdx.x * blockDim.x + threadIdx.x;
    const int n8 = N_NODES * NF / 8;
    if (i >= n8) return;
    const float4* ip = (const float4*)in;
    float4 a = ip[2 * i], b = ip[2 * i + 1];
    uint4 o;
    o.x = (unsigned)f2b(a.x) | ((unsigned)f2b(a.y) << 16);
    o.y = (unsigned)f2b(a.z) | ((unsigned)f2b(a.w) << 16);
    o.z = (unsigned)f2b(b.x) | ((unsigned)f2b(b.y) << 16);
    o.w = (unsigned)f2b(b.z) | ((unsigned)f2b(b.w) << 16);
    ((uint4*)out)[i] = o;
}

// ---------------- weight transpose: Bt[layer][n][k] (bf16) ----------------
__global__ void build_bt(const float* __restrict__ w1l, const float* __restrict__ w1r,
                         const float* __restrict__ w2l, const float* __restrict__ w2r,
                         const float* __restrict__ w3l, const float* __restrict__ w3r,
                         unsigned short* __restrict__ Bt) {
    int i = blockIdx.x * blockDim.x + threadIdx.x;
    if (i >= 3 * 128 * 256) return;
    int layer = i / (128 * 256);
    int r = i % (128 * 256);
    int n = r / 256, k = r % 256;
    const float* wl = (layer == 0) ? w1l : (layer == 1) ? w2l : w3l;
    const float* wr = (layer == 0) ? w1r : (layer == 1) ? w2r : w3r;
    float v = (k < 128) ? wl[k * 128 + n] : wr[(k - 128) * 128 + n];
    Bt[i] = f2b(v);
}

// ---------------- mean aggregation: one wave per node, lane owns 2 feats, 8-deep MLP ----------------
__global__ __launch_bounds__(256) void agg_kernel(const unsigned short* __restrict__ F,
                                                  const int* __restrict__ rowptr,
                                                  const int* __restrict__ eidx,
                                                  unsigned short* __restrict__ M) {
    int node = blockIdx.x * 4 + (threadIdx.x >> 6);
    if (node >= N_NODES) return;
    int lane = threadIdx.x & 63;
    int beg = rowptr[node], end = rowptr[node + 1];
    const unsigned* Fb = (const unsigned*)F;
    float ax = 0.f, ay = 0.f;
    int t = beg;
    for (; t + 8 <= end; t += 8) {
        int s0 = eidx[t], s1 = eidx[t + 1], s2 = eidx[t + 2], s3 = eidx[t + 3];
        int s4 = eidx[t + 4], s5 = eidx[t + 5], s6 = eidx[t + 6], s7 = eidx[t + 7];
        unsigned v0 = Fb[(size_t)s0 * 64 + lane];
        unsigned v1 = Fb[(size_t)s1 * 64 + lane];
        unsigned v2 = Fb[(size_t)s2 * 64 + lane];
        unsigned v3 = Fb[(size_t)s3 * 64 + lane];
        unsigned v4 = Fb[(size_t)s4 * 64 + lane];
        unsigned v5 = Fb[(size_t)s5 * 64 + lane];
        unsigned v6 = Fb[(size_t)s6 * 64 + lane];
        unsigned v7 = Fb[(size_t)s7 * 64 + lane];
        ax += lo16(v0) + lo16(v1) + lo16(v2) + lo16(v3) + lo16(v4) + lo16(v5) + lo16(v6) + lo16(v7);
        ay += hi16(v0) + hi16(v1) + hi16(v2) + hi16(v3) + hi16(v4) + hi16(v5) + hi16(v6) + hi16(v7);
    }
    for (; t + 4 <= end; t += 4) {
        int s0 = eidx[t], s1 = eidx[t + 1], s2 = eidx[t + 2], s3 = eidx[t + 3];
        unsigned v0 = Fb[(size_t)s0 * 64 + lane];
        unsigned v1 = Fb[(size_t)s1 * 64 + lane];
        unsigned v2 = Fb[(size_t)s2 * 64 + lane];
        unsigned v3 = Fb[(size_t)s3 * 64 + lane];
        ax += lo16(v0) + lo16(v1) + lo16(v2) + lo16(v3);
        ay += hi16(v0) + hi16(v1) + hi16(v2) + hi16(v3);
    }
    for (; t < end; ++t) {
        unsigned v = Fb[(size_t)eidx[t] * 64 + lane];
        ax += lo16(v);
        ay += hi16(v);
    }
    float inv = 1.0f / (float)max(end - beg, 1);
    unsigned out = (unsigned)f2b(ax * inv) | ((unsigned)f2b(ay * inv) << 16);
    ((unsigned*)M)[(size_t)node * 64 + lane] = out;
}

// ---------------- GEMM: H = relu([mean|feat] @ Bt^T + b), MFMA 16x16x32 bf16 ----------------
__global__ __launch_bounds__(256) void gemm_kernel(const unsigned short* __restrict__ Am,
                                                   const unsigned short* __restrict__ Ax,
                                                   const unsigned short* __restrict__ Bt,
                                                   const float* __restrict__ bias,
                                                   unsigned short* __restrict__ Out) {
    const int wave = threadIdx.x >> 6, lane = threadIdx.x & 63;
    const int lrow = lane & 15, quad = lane >> 4;
    const int row0 = blockIdx.x * 64 + wave * 16;
    int arow = row0 + lrow;
    if (arow >= N_NODES) arow = N_NODES - 1;

    f32x4 acc[8];
#pragma unroll
    for (int nt = 0; nt < 8; ++nt) acc[nt] = (f32x4){0.f, 0.f, 0.f, 0.f};

#pragma unroll
    for (int kk = 0; kk < 8; ++kk) {
        const int kb = kk * 32 + quad * 8;
        const unsigned short* ap = (kb < 128) ? (Am + (size_t)arow * 128 + kb)
                                              : (Ax + (size_t)arow * 128 + (kb - 128));
        short8 af = *(const short8*)ap;
#pragma unroll
        for (int nt = 0; nt < 8; ++nt) {
            short8 bf = *(const short8*)(Bt + (size_t)(nt * 16 + lrow) * 256 + kb);
            acc[nt] = __builtin_amdgcn_mfma_f32_16x16x32_bf16(af, bf, acc[nt], 0, 0, 0);
        }
    }

#pragma unroll
    for (int nt = 0; nt < 8; ++nt) {
        int col = nt * 16 + lrow;
        float bc = bias[col];
#pragma unroll
        for (int r = 0; r < 4; ++r) {
            int row = row0 + quad * 4 + r;
            if (row < N_NODES) {
                float v = acc[nt][r] + bc;
                v = fmaxf(v, 0.f);
                Out[(size_t)row * 128 + col] = f2b(v);
            }
        }
    }
}

// ---------------- gate ----------------
__global__ __launch_bounds__(256) void gate_kernel(const unsigned short* __restrict__ h,
                                                   const float* __restrict__ gw,
                                                   const float* __restrict__ gb,
                                                   float* __restrict__ gate) {
    int node = blockIdx.x * 4 + (threadIdx.x >> 6);
    if (node >= N_NODES) return;
    int lane = threadIdx.x & 63;
    unsigned hv = ((const unsigned*)h)[(size_t)node * 64 + lane];
    float w0 = gw[2 * lane], w1 = gw[2 * lane + 1];
    float s = lo16(hv) * w0 + hi16(hv) * w1;
#pragma unroll
    for (int o = 32; o; o >>= 1) s += __shfl_down(s, o);
    if (lane == 0) gate[node] = s + gb[0];
}

// ---------------- graph segment bounds ----------------
__global__ __launch_bounds__(1024) void bounds_kernel(const int* __restrict__ batch, int* __restrict__ gstart) {
    int g = threadIdx.x + blockIdx.x * blockDim.x;
    if (g > NG) return;
    int lo = 0, hi = N_NODES;
    while (lo < hi) {
        int mid = (lo + hi) >> 1;
        if (batch[mid] < g) lo = mid + 1; else hi = mid;
    }
    gstart[g] = lo;
}

// ---------------- fused attention-pool + MLP + log_softmax ----------------
__global__ __launch_bounds__(256) void pool_mlp_kernel(const unsigned short* __restrict__ h,
                                                       const float* __restrict__ gate,
                                                       const int* __restrict__ gstart,
                                                       const float* __restrict__ l1w,
                                                       const float* __restrict__ l1b,
                                                       const float* __restrict__ l2w,
                                                       const float* __restrict__ l2b,
                                                       float* __restrict__ out) {
    int wv = threadIdx.x >> 6;
    int g = blockIdx.x * 4 + wv;
    int lane = threadIdx.x & 63;
    __shared__ float pooled_s[4][128];
    __shared__ float hid_s[4][128];
    if (g >= NG) return;

    int beg = gstart[g], end = gstart[g + 1];

    float m = -INFINITY;
    for (int i = beg + lane; i < end; i += 64) m = fmaxf(m, gate[i]);
#pragma unroll
    for (int o = 32; o; o >>= 1) m = fmaxf(m, __shfl_xor(m, o));
    float s = 0.f;
    for (int i = beg + lane; i < end; i += 64) s += expf(gate[i] - m);
#pragma unroll
    for (int o = 32; o; o >>= 1) s += __shfl_xor(s, o);
    float invs = (s > 0.f) ? 1.0f / s : 0.f;

    float ax = 0.f, ay = 0.f;
    const unsigned* hb = (const unsigned*)h;
    int i = beg;
    for (; i + 2 <= end; i += 2) {
        float w0 = expf(gate[i] - m) * invs;
        float w1 = expf(gate[i + 1] - m) * invs;
        unsigned v0 = hb[(size_t)i * 64 + lane];
        unsigned v1 = hb[(size_t)(i + 1) * 64 + lane];
        ax += w0 * lo16(v0) + w1 * lo16(v1);
        ay += w0 * hi16(v0) + w1 * hi16(v1);
    }
    for (; i < end; ++i) {
        float w = expf(gate[i] - m) * invs;
        unsigned v = hb[(size_t)i * 64 + lane];
        ax += w * lo16(v);
        ay += w * hi16(v);
    }
    pooled_s[wv][2 * lane] = ax;
    pooled_s[wv][2 * lane + 1] = ay;

    float h0 = l1b[lane], h1 = l1b[lane + 64];
    for (int k = 0; k < 128; ++k) {
        float pv = pooled_s[wv][k];
        h0 += pv * l1w[k * 128 + lane];
        h1 += pv * l1w[k * 128 + lane + 64];
    }
    hid_s[wv][lane] = fmaxf(h0, 0.f);
    hid_s[wv][lane + 64] = fmaxf(h1, 0.f);

    float o10 = 0.f;
    if (lane < NC) {
        o10 = l2b[lane];
        for (int k = 0; k < 128; ++k) o10 += hid_s[wv][k] * l2w[k * NC + lane];
    }
    float mm = -INFINITY;
#pragma unroll
    for (int j = 0; j < NC; ++j) mm = fmaxf(mm, __shfl(o10, j));
    float ss = 0.f;
#pragma unroll
    for (int j = 0; j < NC; ++j) ss += expf(__shfl(o10, j) - mm);
    float lse = mm + logf(ss);
    if (lane < NC) out[g * NC + lane] = o10 - lse;
}

extern "C" void kernel_launch(void* const* d_in, const int* in_sizes, int n_in,
                              void* d_out, int out_size, void* d_ws, size_t ws_size,
                              hipStream_t stream) {
    const float* x   = (const float*)d_in[0];
    const int* ei    = (const int*)d_in[1];
    const int* batch = (const int*)d_in[2];
    const float* w1l = (const float*)d_in[3];
    const float* b1  = (const float*)d_in[4];
    const float* w1r = (const float*)d_in[5];
    const float* w2l = (const float*)d_in[6];
    const float* b2  = (const float*)d_in[7];
    const float* w2r = (const float*)d_in[8];
    const float* w3l = (const float*)d_in[9];
    const float* b3  = (const float*)d_in[10];
    const float* w3r = (const float*)d_in[11];
    const float* gw  = (const float*)d_in[12];
    const float* gb  = (const float*)d_in[13];
    const float* l1w = (const float*)d_in[14];
    const float* l1b = (const float*)d_in[15];
    const float* l2w = (const float*)d_in[16];
    const float* l2b = (const float*)d_in[17];
    float* out = (float*)d_out;

    const int* src = ei;
    const int* dst = ei + N_EDGES;

    char* base = (char*)d_ws;
    size_t off = 0;
    auto carve = [&](size_t bytes) -> void* {
        void* r = base + off;
        off = (off + bytes + 255) & ~(size_t)255;
        return r;
    };
    int* deg            = (int*)carve((size_t)N_NODES * 4);
    int* rowptr         = (int*)carve((size_t)(N_NODES + 1) * 4);
    int* cursor         = (int*)carve((size_t)N_NODES * 4);
    int* eidx           = (int*)carve((size_t)N_EDGES * 4);
    unsigned short* Bt  = (unsigned short*)carve((size_t)3 * 128 * 256 * 2);
    unsigned short* xb  = (unsigned short*)carve((size_t)N_NODES * NF * 2);
    unsigned short* mn  = (unsigned short*)carve((size_t)N_NODES * NF * 2);
    unsigned short* hA  = (unsigned short*)carve((size_t)N_NODES * NF * 2);
    unsigned short* hB  = (unsigned short*)carve((size_t)N_NODES * NF * 2);
    float* gate         = (float*)carve((size_t)N_NODES * 4);
    int* gstart         = (int*)carve(513 * 4);
    int* bsum           = (int*)carve(256 * 4);
    int* boff           = (int*)carve(256 * 4);

    hipMemsetAsync(deg, 0, (size_t)N_NODES * 4, stream);
    hipMemsetAsync(cursor, 0, (size_t)N_NODES * 4, stream);

    const int EB = (N_EDGES + 255) / 256;  // 6250
    deg_kernel<<<EB, 256, 0, stream>>>(dst, deg);
    scan_blocksum<<<N_SCAN_BLOCKS, 256, 0, stream>>>(deg, bsum);
    scan_partials<<<1, 128, 0, stream>>>(bsum, boff);
    scan_final<<<N_SCAN_BLOCKS, 256, 0, stream>>>(deg, boff, rowptr);
    fill_kernel<<<EB, 256, 0, stream>>>(src, dst, rowptr, cursor, eidx);
    build_bt<<<(3 * 128 * 256 + 255) / 256, 256, 0, stream>>>(w1l, w1r, w2l, w2r, w3l, w3r, Bt);
    cvt_kernel<<<(N_NODES * NF / 8 + 255) / 256, 256, 0, stream>>>(x, xb);

    const int AGG_B = (N_NODES + 3) / 4;    // 25000
    const int GEMM_B = (N_NODES + 63) / 64; // 1563

    agg_kernel<<<AGG_B, 256, 0, stream>>>(xb, rowptr, eidx, mn);
    gemm_kernel<<<GEMM_B, 256, 0, stream>>>(mn, xb, Bt, b1, hA);
    agg_kernel<<<AGG_B, 256, 0, stream>>>(hA, rowptr, eidx, mn);
    gemm_kernel<<<GEMM_B, 256, 0, stream>>>(mn, hA, Bt + 32768, b2, hB);
    agg_kernel<<<AGG_B, 256, 0, stream>>>(hB, rowptr, eidx, mn);
    gemm_kernel<<<GEMM_B, 256, 0, stream>>>(mn, hB, Bt + 65536, b3, hA);

    gate_kernel<<<AGG_B, 256, 0, stream>>>(hA, gw, gb, gate);
    bounds_kernel<<<1, 1024, 0, stream>>>(batch, gstart);
    pool_mlp_kernel<<<(NG + 3) / 4, 256, 0, stream>>>(hA, gate, gstart, l1w, l1b, l2w, l2b, out);
}

// Round 4
// 647.042 us; speedup vs baseline: 1.4496x; 1.1474x over previous
//
#include <hip/hip_runtime.h>
#include <stdint.h>

#define N_NODES 100000
#define N_EDGES 1600000
#define NF 128
#define NG 512
#define NC 10

#define NBUCK ((N_NODES + 255) / 256)  // 391 buckets of 256 nodes
#define EPB 8192                       // edges per block in bucket passes

typedef short short8 __attribute__((ext_vector_type(8)));
typedef float f32x4 __attribute__((ext_vector_type(4)));

__device__ __forceinline__ unsigned short f2b(float f) {
    unsigned u = __float_as_uint(f);
    u += 0x7fffu + ((u >> 16) & 1u);
    return (unsigned short)(u >> 16);
}
__device__ __forceinline__ float lo16(unsigned v) { return __uint_as_float(v << 16); }
__device__ __forceinline__ float hi16(unsigned v) { return __uint_as_float(v & 0xffff0000u); }

// ---------------- CSR build via bucketed counting sort ----------------
// Pass A: per-bucket edge counts
__global__ __launch_bounds__(256) void bucket_count(const int* __restrict__ dst, int* __restrict__ bcount) {
    __shared__ int h[NBUCK];
    for (int i = threadIdx.x; i < NBUCK; i += 256) h[i] = 0;
    __syncthreads();
    const int base = blockIdx.x * EPB;
    const int lim = min(base + EPB, N_EDGES);
    for (int i = base + threadIdx.x; i < lim; i += 256) atomicAdd(&h[dst[i] >> 8], 1);
    __syncthreads();
    for (int i = threadIdx.x; i < NBUCK; i += 256)
        if (h[i]) atomicAdd(&bcount[i], h[i]);
}

// Pass A2: exclusive scan of bucket counts -> bases + write cursors
__global__ __launch_bounds__(512) void bucket_scan(const int* __restrict__ bcount, int* __restrict__ bbase,
                                                   int* __restrict__ gcursor, int* __restrict__ rowptr) {
    __shared__ int sh[512];
    const int t = threadIdx.x;
    int v = (t < NBUCK) ? bcount[t] : 0;
    sh[t] = v;
    __syncthreads();
    for (int off = 1; off < 512; off <<= 1) {
        int u = (t >= off) ? sh[t - off] : 0;
        __syncthreads();
        sh[t] += u;
        __syncthreads();
    }
    if (t < NBUCK) {
        int e = sh[t] - v;
        bbase[t] = e;
        gcursor[t] = e;
    }
    if (t == NBUCK - 1) bbase[NBUCK] = sh[t];
    if (t == 0) rowptr[N_NODES] = N_EDGES;
}

// Pass B: scatter packed records into bucket-contiguous regions (streaming cursors)
__global__ __launch_bounds__(256) void bucket_scatter(const int* __restrict__ src, const int* __restrict__ dst,
                                                      int* __restrict__ gcursor, unsigned* __restrict__ brec) {
    __shared__ int h[NBUCK];
    for (int i = threadIdx.x; i < NBUCK; i += 256) h[i] = 0;
    __syncthreads();
    const int base = blockIdx.x * EPB;
    const int lim = min(base + EPB, N_EDGES);
    for (int i = base + threadIdx.x; i < lim; i += 256) atomicAdd(&h[dst[i] >> 8], 1);
    __syncthreads();
    for (int i = threadIdx.x; i < NBUCK; i += 256) {
        int c = h[i];
        if (c) h[i] = atomicAdd(&gcursor[i], c);  // reserve contiguous chunk; h becomes absolute cursor
    }
    __syncthreads();
    for (int i = base + threadIdx.x; i < lim; i += 256) {
        int d = dst[i];
        int pos = atomicAdd(&h[d >> 8], 1);
        brec[pos] = ((unsigned)(d & 255) << 17) | (unsigned)src[i];  // src < 2^17
    }
}

// Pass C: per bucket -> per-node counts, rowptr, and L2-local eidx placement
__global__ __launch_bounds__(256) void bucket_fill(const unsigned* __restrict__ brec, const int* __restrict__ bbase,
                                                   int* __restrict__ rowptr, int* __restrict__ eidx) {
    __shared__ int nh[256];
    __shared__ int sc[256];
    const int b = blockIdx.x, t = threadIdx.x;
    const int beg = bbase[b], end = bbase[b + 1];
    nh[t] = 0;
    __syncthreads();
    for (int i = beg + t; i < end; i += 256) atomicAdd(&nh[brec[i] >> 17], 1);
    __syncthreads();
    int cnt = nh[t];
    sc[t] = cnt;
    __syncthreads();
    for (int off = 1; off < 256; off <<= 1) {
        int u = (t >= off) ? sc[t - off] : 0;
        __syncthreads();
        sc[t] += u;
        __syncthreads();
    }
    int excl = sc[t] - cnt;
    int node = b * 256 + t;
    if (node < N_NODES) rowptr[node] = beg + excl;
    nh[t] = beg + excl;  // reuse as absolute cursor
    __syncthreads();
    for (int i = beg + t; i < end; i += 256) {
        unsigned r = brec[i];
        int pos = atomicAdd(&nh[r >> 17], 1);
        eidx[pos] = (int)(r & 0x1FFFFu);
    }
}

// ---------------- x (f32) -> bf16, 8 elems/thread ----------------
__global__ __launch_bounds__(256) void cvt_kernel(const float* __restrict__ in, unsigned short* __restrict__ out) {
    int i = blockIdx.x * blockDim.x + threadIdx.x;
    const int n8 = N_NODES * NF / 8;
    if (i >= n8) return;
    const float4* ip = (const float4*)in;
    float4 a = ip[2 * i], b = ip[2 * i + 1];
    uint4 o;
    o.x = (unsigned)f2b(a.x) | ((unsigned)f2b(a.y) << 16);
    o.y = (unsigned)f2b(a.z) | ((unsigned)f2b(a.w) << 16);
    o.z = (unsigned)f2b(b.x) | ((unsigned)f2b(b.y) << 16);
    o.w = (unsigned)f2b(b.z) | ((unsigned)f2b(b.w) << 16);
    ((uint4*)out)[i] = o;
}

// ---------------- weight transpose: Bt[layer][n][k] (bf16) ----------------
__global__ void build_bt(const float* __restrict__ w1l, const float* __restrict__ w1r,
                         const float* __restrict__ w2l, const float* __restrict__ w2r,
                         const float* __restrict__ w3l, const float* __restrict__ w3r,
                         unsigned short* __restrict__ Bt) {
    int i = blockIdx.x * blockDim.x + threadIdx.x;
    if (i >= 3 * 128 * 256) return;
    int layer = i / (128 * 256);
    int r = i % (128 * 256);
    int n = r / 256, k = r % 256;
    const float* wl = (layer == 0) ? w1l : (layer == 1) ? w2l : w3l;
    const float* wr = (layer == 0) ? w1r : (layer == 1) ? w2r : w3r;
    float v = (k < 128) ? wl[k * 128 + n] : wr[(k - 128) * 128 + n];
    Bt[i] = f2b(v);
}

// ---------------- mean aggregation: one wave per node; quad handles one row, lane reads 16B ----------------
__global__ __launch_bounds__(256) void agg_kernel(const unsigned short* __restrict__ F,
                                                  const int* __restrict__ rowptr,
                                                  const int* __restrict__ eidx,
                                                  unsigned short* __restrict__ M) {
    int node = blockIdx.x * 4 + (threadIdx.x >> 6);
    if (node >= N_NODES) return;
    const int lane = threadIdx.x & 63;
    const int quad = lane >> 4, ql = lane & 15;
    const int beg = rowptr[node], end = rowptr[node + 1];
    const uint4* F4 = (const uint4*)F;  // row stride = 16 uint4 (256 B)

    float a0 = 0.f, a1 = 0.f, a2 = 0.f, a3 = 0.f, a4 = 0.f, a5 = 0.f, a6 = 0.f, a7 = 0.f;
    int t = beg;
    for (; t + 8 <= end; t += 8) {
        int r0 = eidx[t + quad];
        int r1 = eidx[t + 4 + quad];
        uint4 v0 = F4[(size_t)r0 * 16 + ql];
        uint4 v1 = F4[(size_t)r1 * 16 + ql];
        a0 += lo16(v0.x) + lo16(v1.x);
        a1 += hi16(v0.x) + hi16(v1.x);
        a2 += lo16(v0.y) + lo16(v1.y);
        a3 += hi16(v0.y) + hi16(v1.y);
        a4 += lo16(v0.z) + lo16(v1.z);
        a5 += hi16(v0.z) + hi16(v1.z);
        a6 += lo16(v0.w) + lo16(v1.w);
        a7 += hi16(v0.w) + hi16(v1.w);
    }
    if (t + 4 <= end) {
        int r0 = eidx[t + quad];
        uint4 v0 = F4[(size_t)r0 * 16 + ql];
        a0 += lo16(v0.x); a1 += hi16(v0.x);
        a2 += lo16(v0.y); a3 += hi16(v0.y);
        a4 += lo16(v0.z); a5 += hi16(v0.z);
        a6 += lo16(v0.w); a7 += hi16(v0.w);
        t += 4;
    }
    int rem = end - t;
    if (rem > 0) {
        int r0 = eidx[t + min(quad, rem - 1)];
        uint4 v0 = F4[(size_t)r0 * 16 + ql];
        if (quad < rem) {
            a0 += lo16(v0.x); a1 += hi16(v0.x);
            a2 += lo16(v0.y); a3 += hi16(v0.y);
            a4 += lo16(v0.z); a5 += hi16(v0.z);
            a6 += lo16(v0.w); a7 += hi16(v0.w);
        }
    }
    // reduce the 4 quads
    a0 += __shfl_xor(a0, 16); a0 += __shfl_xor(a0, 32);
    a1 += __shfl_xor(a1, 16); a1 += __shfl_xor(a1, 32);
    a2 += __shfl_xor(a2, 16); a2 += __shfl_xor(a2, 32);
    a3 += __shfl_xor(a3, 16); a3 += __shfl_xor(a3, 32);
    a4 += __shfl_xor(a4, 16); a4 += __shfl_xor(a4, 32);
    a5 += __shfl_xor(a5, 16); a5 += __shfl_xor(a5, 32);
    a6 += __shfl_xor(a6, 16); a6 += __shfl_xor(a6, 32);
    a7 += __shfl_xor(a7, 16); a7 += __shfl_xor(a7, 32);

    if (quad == 0) {
        float inv = 1.0f / (float)max(end - beg, 1);
        uint4 o;
        o.x = (unsigned)f2b(a0 * inv) | ((unsigned)f2b(a1 * inv) << 16);
        o.y = (unsigned)f2b(a2 * inv) | ((unsigned)f2b(a3 * inv) << 16);
        o.z = (unsigned)f2b(a4 * inv) | ((unsigned)f2b(a5 * inv) << 16);
        o.w = (unsigned)f2b(a6 * inv) | ((unsigned)f2b(a7 * inv) << 16);
        ((uint4*)M)[(size_t)node * 16 + ql] = o;
    }
}

// ---------------- GEMM: H = relu([mean|feat] @ Bt^T + b), MFMA 16x16x32 bf16 ----------------
__global__ __launch_bounds__(256) void gemm_kernel(const unsigned short* __restrict__ Am,
                                                   const unsigned short* __restrict__ Ax,
                                                   const unsigned short* __restrict__ Bt,
                                                   const float* __restrict__ bias,
                                                   unsigned short* __restrict__ Out) {
    const int wave = threadIdx.x >> 6, lane = threadIdx.x & 63;
    const int lrow = lane & 15, quad = lane >> 4;
    const int row0 = blockIdx.x * 64 + wave * 16;
    int arow = row0 + lrow;
    if (arow >= N_NODES) arow = N_NODES - 1;

    f32x4 acc[8];
#pragma unroll
    for (int nt = 0; nt < 8; ++nt) acc[nt] = (f32x4){0.f, 0.f, 0.f, 0.f};

#pragma unroll
    for (int kk = 0; kk < 8; ++kk) {
        const int kb = kk * 32 + quad * 8;
        const unsigned short* ap = (kb < 128) ? (Am + (size_t)arow * 128 + kb)
                                              : (Ax + (size_t)arow * 128 + (kb - 128));
        short8 af = *(const short8*)ap;
#pragma unroll
        for (int nt = 0; nt < 8; ++nt) {
            short8 bf = *(const short8*)(Bt + (size_t)(nt * 16 + lrow) * 256 + kb);
            acc[nt] = __builtin_amdgcn_mfma_f32_16x16x32_bf16(af, bf, acc[nt], 0, 0, 0);
        }
    }

#pragma unroll
    for (int nt = 0; nt < 8; ++nt) {
        int col = nt * 16 + lrow;
        float bc = bias[col];
#pragma unroll
        for (int r = 0; r < 4; ++r) {
            int row = row0 + quad * 4 + r;
            if (row < N_NODES) {
                float v = acc[nt][r] + bc;
                v = fmaxf(v, 0.f);
                Out[(size_t)row * 128 + col] = f2b(v);
            }
        }
    }
}

// ---------------- gate ----------------
__global__ __launch_bounds__(256) void gate_kernel(const unsigned short* __restrict__ h,
                                                   const float* __restrict__ gw,
                                                   const float* __restrict__ gb,
                                                   float* __restrict__ gate) {
    int node = blockIdx.x * 4 + (threadIdx.x >> 6);
    if (node >= N_NODES) return;
    int lane = threadIdx.x & 63;
    unsigned hv = ((const unsigned*)h)[(size_t)node * 64 + lane];
    float w0 = gw[2 * lane], w1 = gw[2 * lane + 1];
    float s = lo16(hv) * w0 + hi16(hv) * w1;
#pragma unroll
    for (int o = 32; o; o >>= 1) s += __shfl_down(s, o);
    if (lane == 0) gate[node] = s + gb[0];
}

// ---------------- graph segment bounds ----------------
__global__ __launch_bounds__(1024) void bounds_kernel(const int* __restrict__ batch, int* __restrict__ gstart) {
    int g = threadIdx.x + blockIdx.x * blockDim.x;
    if (g > NG) return;
    int lo = 0, hi = N_NODES;
    while (lo < hi) {
        int mid = (lo + hi) >> 1;
        if (batch[mid] < g) lo = mid + 1; else hi = mid;
    }
    gstart[g] = lo;
}

// ---------------- fused attention-pool + MLP + log_softmax ----------------
__global__ __launch_bounds__(256) void pool_mlp_kernel(const unsigned short* __restrict__ h,
                                                       const float* __restrict__ gate,
                                                       const int* __restrict__ gstart,
                                                       const float* __restrict__ l1w,
                                                       const float* __restrict__ l1b,
                                                       const float* __restrict__ l2w,
                                                       const float* __restrict__ l2b,
                                                       float* __restrict__ out) {
    int wv = threadIdx.x >> 6;
    int g = blockIdx.x * 4 + wv;
    int lane = threadIdx.x & 63;
    __shared__ float pooled_s[4][128];
    __shared__ float hid_s[4][128];
    if (g >= NG) return;

    int beg = gstart[g], end = gstart[g + 1];

    float m = -INFINITY;
    for (int i = beg + lane; i < end; i += 64) m = fmaxf(m, gate[i]);
#pragma unroll
    for (int o = 32; o; o >>= 1) m = fmaxf(m, __shfl_xor(m, o));
    float s = 0.f;
    for (int i = beg + lane; i < end; i += 64) s += expf(gate[i] - m);
#pragma unroll
    for (int o = 32; o; o >>= 1) s += __shfl_xor(s, o);
    float invs = (s > 0.f) ? 1.0f / s : 0.f;

    float ax = 0.f, ay = 0.f;
    const unsigned* hb = (const unsigned*)h;
    int i = beg;
    for (; i + 2 <= end; i += 2) {
        float w0 = expf(gate[i] - m) * invs;
        float w1 = expf(gate[i + 1] - m) * invs;
        unsigned v0 = hb[(size_t)i * 64 + lane];
        unsigned v1 = hb[(size_t)(i + 1) * 64 + lane];
        ax += w0 * lo16(v0) + w1 * lo16(v1);
        ay += w0 * hi16(v0) + w1 * hi16(v1);
    }
    for (; i < end; ++i) {
        float w = expf(gate[i] - m) * invs;
        unsigned v = hb[(size_t)i * 64 + lane];
        ax += w * lo16(v);
        ay += w * hi16(v);
    }
    pooled_s[wv][2 * lane] = ax;
    pooled_s[wv][2 * lane + 1] = ay;

    float h0 = l1b[lane], h1 = l1b[lane + 64];
    for (int k = 0; k < 128; ++k) {
        float pv = pooled_s[wv][k];
        h0 += pv * l1w[k * 128 + lane];
        h1 += pv * l1w[k * 128 + lane + 64];
    }
    hid_s[wv][lane] = fmaxf(h0, 0.f);
    hid_s[wv][lane + 64] = fmaxf(h1, 0.f);

    float o10 = 0.f;
    if (lane < NC) {
        o10 = l2b[lane];
        for (int k = 0; k < 128; ++k) o10 += hid_s[wv][k] * l2w[k * NC + lane];
    }
    float mm = -INFINITY;
#pragma unroll
    for (int j = 0; j < NC; ++j) mm = fmaxf(mm, __shfl(o10, j));
    float ss = 0.f;
#pragma unroll
    for (int j = 0; j < NC; ++j) ss += expf(__shfl(o10, j) - mm);
    float lse = mm + logf(ss);
    if (lane < NC) out[g * NC + lane] = o10 - lse;
}

extern "C" void kernel_launch(void* const* d_in, const int* in_sizes, int n_in,
                              void* d_out, int out_size, void* d_ws, size_t ws_size,
                              hipStream_t stream) {
    const float* x   = (const float*)d_in[0];
    const int* ei    = (const int*)d_in[1];
    const int* batch = (const int*)d_in[2];
    const float* w1l = (const float*)d_in[3];
    const float* b1  = (const float*)d_in[4];
    const float* w1r = (const float*)d_in[5];
    const float* w2l = (const float*)d_in[6];
    const float* b2  = (const float*)d_in[7];
    const float* w2r = (const float*)d_in[8];
    const float* w3l = (const float*)d_in[9];
    const float* b3  = (const float*)d_in[10];
    const float* w3r = (const float*)d_in[11];
    const float* gw  = (const float*)d_in[12];
    const float* gb  = (const float*)d_in[13];
    const float* l1w = (const float*)d_in[14];
    const float* l1b = (const float*)d_in[15];
    const float* l2w = (const float*)d_in[16];
    const float* l2b = (const float*)d_in[17];
    float* out = (float*)d_out;

    const int* src = ei;
    const int* dst = ei + N_EDGES;

    char* base = (char*)d_ws;
    size_t off = 0;
    auto carve = [&](size_t bytes) -> void* {
        void* r = base + off;
        off = (off + bytes + 255) & ~(size_t)255;
        return r;
    };
    int* rowptr         = (int*)carve((size_t)(N_NODES + 1) * 4);
    int* eidx           = (int*)carve((size_t)N_EDGES * 4);
    unsigned short* Bt  = (unsigned short*)carve((size_t)3 * 128 * 256 * 2);
    unsigned short* xb  = (unsigned short*)carve((size_t)N_NODES * NF * 2);
    unsigned short* mn  = (unsigned short*)carve((size_t)N_NODES * NF * 2);
    unsigned short* hA  = (unsigned short*)carve((size_t)N_NODES * NF * 2);
    unsigned short* hB  = (unsigned short*)carve((size_t)N_NODES * NF * 2);
    float* gate         = (float*)carve((size_t)N_NODES * 4);
    int* gstart         = (int*)carve(513 * 4);
    int* bcount         = (int*)carve((NBUCK + 1) * 4);
    int* bbase          = (int*)carve((NBUCK + 1) * 4);
    int* gcursor        = (int*)carve((NBUCK + 1) * 4);
    unsigned* brec      = (unsigned*)mn;  // alias: mn is dead until the first agg_kernel

    hipMemsetAsync(bcount, 0, (size_t)NBUCK * 4, stream);

    const int BUCK_B = (N_EDGES + EPB - 1) / EPB;  // 196
    bucket_count<<<BUCK_B, 256, 0, stream>>>(dst, bcount);
    bucket_scan<<<1, 512, 0, stream>>>(bcount, bbase, gcursor, rowptr);
    bucket_scatter<<<BUCK_B, 256, 0, stream>>>(src, dst, gcursor, brec);
    bucket_fill<<<NBUCK, 256, 0, stream>>>(brec, bbase, rowptr, eidx);

    build_bt<<<(3 * 128 * 256 + 255) / 256, 256, 0, stream>>>(w1l, w1r, w2l, w2r, w3l, w3r, Bt);
    cvt_kernel<<<(N_NODES * NF / 8 + 255) / 256, 256, 0, stream>>>(x, xb);

    const int AGG_B = (N_NODES + 3) / 4;    // 25000
    const int GEMM_B = (N_NODES + 63) / 64; // 1563

    agg_kernel<<<AGG_B, 256, 0, stream>>>(xb, rowptr, eidx, mn);
    gemm_kernel<<<GEMM_B, 256, 0, stream>>>(mn, xb, Bt, b1, hA);
    agg_kernel<<<AGG_B, 256, 0, stream>>>(hA, rowptr, eidx, mn);
    gemm_kernel<<<GEMM_B, 256, 0, stream>>>(mn, hA, Bt + 32768, b2, hB);
    agg_kernel<<<AGG_B, 256, 0, stream>>>(hB, rowptr, eidx, mn);
    gemm_kernel<<<GEMM_B, 256, 0, stream>>>(mn, hB, Bt + 65536, b3, hA);

    gate_kernel<<<AGG_B, 256, 0, stream>>>(hA, gw, gb, gate);
    bounds_kernel<<<1, 1024, 0, stream>>>(batch, gstart);
    pool_mlp_kernel<<<(NG + 3) / 4, 256, 0, stream>>>(hA, gate, gstart, l1w, l1b, l2w, l2b, out);
}

// Round 5
// 540.323 us; speedup vs baseline: 1.7359x; 1.1975x over previous
//
#include <hip/hip_runtime.h>
#include <stdint.h>

#define N_NODES 100000
#define N_EDGES 1600000
#define NF 128
#define NG 512
#define NC 10

#define NBUCK ((N_NODES + 255) / 256)  // 391 buckets of 256 nodes
#define EPB 8192                       // edges per block in bucket passes

#define BM 128       // gemm block rows
#define LDS_STRIDE 40  // shorts per LDS row (32 data + 8 pad) -> 80 B

typedef short short8 __attribute__((ext_vector_type(8)));
typedef float f32x4 __attribute__((ext_vector_type(4)));

__device__ __forceinline__ unsigned short f2b(float f) {
    unsigned u = __float_as_uint(f);
    u += 0x7fffu + ((u >> 16) & 1u);
    return (unsigned short)(u >> 16);
}
__device__ __forceinline__ float lo16(unsigned v) { return __uint_as_float(v << 16); }
__device__ __forceinline__ float hi16(unsigned v) { return __uint_as_float(v & 0xffff0000u); }

// ---------------- CSR build via bucketed counting sort ----------------
__global__ __launch_bounds__(256) void bucket_count(const int* __restrict__ dst, int* __restrict__ bcount) {
    __shared__ int h[NBUCK];
    for (int i = threadIdx.x; i < NBUCK; i += 256) h[i] = 0;
    __syncthreads();
    const int base = blockIdx.x * EPB;
    const int lim = min(base + EPB, N_EDGES);
    for (int i = base + threadIdx.x; i < lim; i += 256) atomicAdd(&h[dst[i] >> 8], 1);
    __syncthreads();
    for (int i = threadIdx.x; i < NBUCK; i += 256)
        if (h[i]) atomicAdd(&bcount[i], h[i]);
}

__global__ __launch_bounds__(512) void bucket_scan(const int* __restrict__ bcount, int* __restrict__ bbase,
                                                   int* __restrict__ gcursor, int* __restrict__ rowptr) {
    __shared__ int sh[512];
    const int t = threadIdx.x;
    int v = (t < NBUCK) ? bcount[t] : 0;
    sh[t] = v;
    __syncthreads();
    for (int off = 1; off < 512; off <<= 1) {
        int u = (t >= off) ? sh[t - off] : 0;
        __syncthreads();
        sh[t] += u;
        __syncthreads();
    }
    if (t < NBUCK) {
        int e = sh[t] - v;
        bbase[t] = e;
        gcursor[t] = e;
    }
    if (t == NBUCK - 1) bbase[NBUCK] = sh[t];
    if (t == 0) rowptr[N_NODES] = N_EDGES;
}

__global__ __launch_bounds__(256) void bucket_scatter(const int* __restrict__ src, const int* __restrict__ dst,
                                                      int* __restrict__ gcursor, unsigned* __restrict__ brec) {
    __shared__ int h[NBUCK];
    for (int i = threadIdx.x; i < NBUCK; i += 256) h[i] = 0;
    __syncthreads();
    const int base = blockIdx.x * EPB;
    const int lim = min(base + EPB, N_EDGES);
    for (int i = base + threadIdx.x; i < lim; i += 256) atomicAdd(&h[dst[i] >> 8], 1);
    __syncthreads();
    for (int i = threadIdx.x; i < NBUCK; i += 256) {
        int c = h[i];
        if (c) h[i] = atomicAdd(&gcursor[i], c);
    }
    __syncthreads();
    for (int i = base + threadIdx.x; i < lim; i += 256) {
        int d = dst[i];
        int pos = atomicAdd(&h[d >> 8], 1);
        brec[pos] = ((unsigned)(d & 255) << 17) | (unsigned)src[i];
    }
}

__global__ __launch_bounds__(256) void bucket_fill(const unsigned* __restrict__ brec, const int* __restrict__ bbase,
                                                   int* __restrict__ rowptr, int* __restrict__ eidx) {
    __shared__ int nh[256];
    __shared__ int sc[256];
    const int b = blockIdx.x, t = threadIdx.x;
    const int beg = bbase[b], end = bbase[b + 1];
    nh[t] = 0;
    __syncthreads();
    for (int i = beg + t; i < end; i += 256) atomicAdd(&nh[brec[i] >> 17], 1);
    __syncthreads();
    int cnt = nh[t];
    sc[t] = cnt;
    __syncthreads();
    for (int off = 1; off < 256; off <<= 1) {
        int u = (t >= off) ? sc[t - off] : 0;
        __syncthreads();
        sc[t] += u;
        __syncthreads();
    }
    int excl = sc[t] - cnt;
    int node = b * 256 + t;
    if (node < N_NODES) rowptr[node] = beg + excl;
    nh[t] = beg + excl;
    __syncthreads();
    for (int i = beg + t; i < end; i += 256) {
        unsigned r = brec[i];
        int pos = atomicAdd(&nh[r >> 17], 1);
        eidx[pos] = (int)(r & 0x1FFFFu);
    }
}

// ---------------- x (f32) -> bf16 ----------------
__global__ __launch_bounds__(256) void cvt_kernel(const float* __restrict__ in, unsigned short* __restrict__ out) {
    int i = blockIdx.x * blockDim.x + threadIdx.x;
    const int n8 = N_NODES * NF / 8;
    if (i >= n8) return;
    const float4* ip = (const float4*)in;
    float4 a = ip[2 * i], b = ip[2 * i + 1];
    uint4 o;
    o.x = (unsigned)f2b(a.x) | ((unsigned)f2b(a.y) << 16);
    o.y = (unsigned)f2b(a.z) | ((unsigned)f2b(a.w) << 16);
    o.z = (unsigned)f2b(b.x) | ((unsigned)f2b(b.y) << 16);
    o.w = (unsigned)f2b(b.z) | ((unsigned)f2b(b.w) << 16);
    ((uint4*)out)[i] = o;
}

// ---------------- weight transpose: Bt[layer][n][k] (bf16) ----------------
__global__ void build_bt(const float* __restrict__ w1l, const float* __restrict__ w1r,
                         const float* __restrict__ w2l, const float* __restrict__ w2r,
                         const float* __restrict__ w3l, const float* __restrict__ w3r,
                         unsigned short* __restrict__ Bt) {
    int i = blockIdx.x * blockDim.x + threadIdx.x;
    if (i >= 3 * 128 * 256) return;
    int layer = i / (128 * 256);
    int r = i % (128 * 256);
    int n = r / 256, k = r % 256;
    const float* wl = (layer == 0) ? w1l : (layer == 1) ? w2l : w3l;
    const float* wr = (layer == 0) ? w1r : (layer == 1) ? w2r : w3r;
    float v = (k < 128) ? wl[k * 128 + n] : wr[(k - 128) * 128 + n];
    Bt[i] = f2b(v);
}

// ---------------- mean aggregation: one wave per node; quad handles one row, lane reads 16B ----------------
__global__ __launch_bounds__(256) void agg_kernel(const unsigned short* __restrict__ F,
                                                  const int* __restrict__ rowptr,
                                                  const int* __restrict__ eidx,
                                                  unsigned short* __restrict__ M) {
    int node = blockIdx.x * 4 + (threadIdx.x >> 6);
    if (node >= N_NODES) return;
    const int lane = threadIdx.x & 63;
    const int quad = lane >> 4, ql = lane & 15;
    const int beg = rowptr[node], end = rowptr[node + 1];
    const uint4* F4 = (const uint4*)F;

    float a0 = 0.f, a1 = 0.f, a2 = 0.f, a3 = 0.f, a4 = 0.f, a5 = 0.f, a6 = 0.f, a7 = 0.f;
    int t = beg;
    for (; t + 8 <= end; t += 8) {
        int r0 = eidx[t + quad];
        int r1 = eidx[t + 4 + quad];
        uint4 v0 = F4[(size_t)r0 * 16 + ql];
        uint4 v1 = F4[(size_t)r1 * 16 + ql];
        a0 += lo16(v0.x) + lo16(v1.x);
        a1 += hi16(v0.x) + hi16(v1.x);
        a2 += lo16(v0.y) + lo16(v1.y);
        a3 += hi16(v0.y) + hi16(v1.y);
        a4 += lo16(v0.z) + lo16(v1.z);
        a5 += hi16(v0.z) + hi16(v1.z);
        a6 += lo16(v0.w) + lo16(v1.w);
        a7 += hi16(v0.w) + hi16(v1.w);
    }
    if (t + 4 <= end) {
        int r0 = eidx[t + quad];
        uint4 v0 = F4[(size_t)r0 * 16 + ql];
        a0 += lo16(v0.x); a1 += hi16(v0.x);
        a2 += lo16(v0.y); a3 += hi16(v0.y);
        a4 += lo16(v0.z); a5 += hi16(v0.z);
        a6 += lo16(v0.w); a7 += hi16(v0.w);
        t += 4;
    }
    int rem = end - t;
    if (rem > 0) {
        int r0 = eidx[t + min(quad, rem - 1)];
        uint4 v0 = F4[(size_t)r0 * 16 + ql];
        if (quad < rem) {
            a0 += lo16(v0.x); a1 += hi16(v0.x);
            a2 += lo16(v0.y); a3 += hi16(v0.y);
            a4 += lo16(v0.z); a5 += hi16(v0.z);
            a6 += lo16(v0.w); a7 += hi16(v0.w);
        }
    }
    a0 += __shfl_xor(a0, 16); a0 += __shfl_xor(a0, 32);
    a1 += __shfl_xor(a1, 16); a1 += __shfl_xor(a1, 32);
    a2 += __shfl_xor(a2, 16); a2 += __shfl_xor(a2, 32);
    a3 += __shfl_xor(a3, 16); a3 += __shfl_xor(a3, 32);
    a4 += __shfl_xor(a4, 16); a4 += __shfl_xor(a4, 32);
    a5 += __shfl_xor(a5, 16); a5 += __shfl_xor(a5, 32);
    a6 += __shfl_xor(a6, 16); a6 += __shfl_xor(a6, 32);
    a7 += __shfl_xor(a7, 16); a7 += __shfl_xor(a7, 32);

    if (quad == 0) {
        float inv = 1.0f / (float)max(end - beg, 1);
        uint4 o;
        o.x = (unsigned)f2b(a0 * inv) | ((unsigned)f2b(a1 * inv) << 16);
        o.y = (unsigned)f2b(a2 * inv) | ((unsigned)f2b(a3 * inv) << 16);
        o.z = (unsigned)f2b(a4 * inv) | ((unsigned)f2b(a5 * inv) << 16);
        o.w = (unsigned)f2b(a6 * inv) | ((unsigned)f2b(a7 * inv) << 16);
        ((uint4*)M)[(size_t)node * 16 + ql] = o;
    }
}

// ---------------- GEMM: H = relu([mean|feat] @ Bt^T + b) ----------------
// LDS-staged m97-style: 128x128 tile, 2x2 waves of 4x4 16x16x32 MFMA tiles, BK=32, 8 chunks.
__global__ __launch_bounds__(256) void gemm_kernel(const unsigned short* __restrict__ Am,
                                                   const unsigned short* __restrict__ Ax,
                                                   const unsigned short* __restrict__ Bt,
                                                   const float* __restrict__ bias,
                                                   unsigned short* __restrict__ Out) {
    const int t = threadIdx.x;
    const int wave = t >> 6, lane = t & 63;
    const int wr = wave >> 1, wc = wave & 1;
    const int lrow = lane & 15, quad = lane >> 4;
    const int row0 = blockIdx.x * BM;

    __shared__ __attribute__((aligned(16))) unsigned short As[128 * LDS_STRIDE];
    __shared__ __attribute__((aligned(16))) unsigned short Bs[128 * LDS_STRIDE];

    f32x4 acc[4][4];
#pragma unroll
    for (int i = 0; i < 4; ++i)
#pragma unroll
        for (int j = 0; j < 4; ++j) acc[i][j] = (f32x4){0.f, 0.f, 0.f, 0.f};

    // staging units: u in [0,512), r = u>>2, seg = u&3 (16B each); thread handles u=t, u=t+256
    const int rA0 = t >> 2, segA0 = t & 3;
    const int rA1 = (t + 256) >> 2, segA1 = t & 3;  // (t+256)&3 == t&3

    for (int c = 0; c < 8; ++c) {
        const unsigned short* Aarr = (c < 4) ? Am : Ax;
        const int kcol = (c & 3) * 32;

        int g0 = row0 + rA0; if (g0 > N_NODES - 1) g0 = N_NODES - 1;
        int g1 = row0 + rA1; if (g1 > N_NODES - 1) g1 = N_NODES - 1;
        uint4 va0 = *(const uint4*)(Aarr + (size_t)g0 * 128 + kcol + segA0 * 8);
        uint4 va1 = *(const uint4*)(Aarr + (size_t)g1 * 128 + kcol + segA1 * 8);
        uint4 vb0 = *(const uint4*)(Bt + (size_t)rA0 * 256 + c * 32 + segA0 * 8);
        uint4 vb1 = *(const uint4*)(Bt + (size_t)rA1 * 256 + c * 32 + segA1 * 8);

        __syncthreads();  // previous chunk's LDS reads complete
        *(uint4*)(As + rA0 * LDS_STRIDE + segA0 * 8) = va0;
        *(uint4*)(As + rA1 * LDS_STRIDE + segA1 * 8) = va1;
        *(uint4*)(Bs + rA0 * LDS_STRIDE + segA0 * 8) = vb0;
        *(uint4*)(Bs + rA1 * LDS_STRIDE + segA1 * 8) = vb1;
        __syncthreads();  // staged data visible

        short8 af[4], bf[4];
#pragma unroll
        for (int i = 0; i < 4; ++i) {
            af[i] = *(const short8*)(As + (wr * 64 + i * 16 + lrow) * LDS_STRIDE + quad * 8);
            bf[i] = *(const short8*)(Bs + (wc * 64 + i * 16 + lrow) * LDS_STRIDE + quad * 8);
        }
#pragma unroll
        for (int i = 0; i < 4; ++i)
#pragma unroll
            for (int j = 0; j < 4; ++j)
                acc[i][j] = __builtin_amdgcn_mfma_f32_16x16x32_bf16(af[i], bf[j], acc[i][j], 0, 0, 0);
    }

#pragma unroll
    for (int j = 0; j < 4; ++j) {
        int col = wc * 64 + j * 16 + lrow;
        float bc = bias[col];
#pragma unroll
        for (int i = 0; i < 4; ++i) {
            int rbase = row0 + wr * 64 + i * 16 + quad * 4;
#pragma unroll
            for (int k = 0; k < 4; ++k) {
                int row = rbase + k;
                if (row < N_NODES) {
                    float v = fmaxf(acc[i][j][k] + bc, 0.f);
                    Out[(size_t)row * 128 + col] = f2b(v);
                }
            }
        }
    }
}

// ---------------- gate ----------------
__global__ __launch_bounds__(256) void gate_kernel(const unsigned short* __restrict__ h,
                                                   const float* __restrict__ gw,
                                                   const float* __restrict__ gb,
                                                   float* __restrict__ gate) {
    int node = blockIdx.x * 4 + (threadIdx.x >> 6);
    if (node >= N_NODES) return;
    int lane = threadIdx.x & 63;
    unsigned hv = ((const unsigned*)h)[(size_t)node * 64 + lane];
    float w0 = gw[2 * lane], w1 = gw[2 * lane + 1];
    float s = lo16(hv) * w0 + hi16(hv) * w1;
#pragma unroll
    for (int o = 32; o; o >>= 1) s += __shfl_down(s, o);
    if (lane == 0) gate[node] = s + gb[0];
}

// ---------------- graph segment bounds ----------------
__global__ __launch_bounds__(1024) void bounds_kernel(const int* __restrict__ batch, int* __restrict__ gstart) {
    int g = threadIdx.x + blockIdx.x * blockDim.x;
    if (g > NG) return;
    int lo = 0, hi = N_NODES;
    while (lo < hi) {
        int mid = (lo + hi) >> 1;
        if (batch[mid] < g) lo = mid + 1; else hi = mid;
    }
    gstart[g] = lo;
}

// ---------------- fused attention-pool + MLP + log_softmax ----------------
__global__ __launch_bounds__(256) void pool_mlp_kernel(const unsigned short* __restrict__ h,
                                                       const float* __restrict__ gate,
                                                       const int* __restrict__ gstart,
                                                       const float* __restrict__ l1w,
                                                       const float* __restrict__ l1b,
                                                       const float* __restrict__ l2w,
                                                       const float* __restrict__ l2b,
                                                       float* __restrict__ out) {
    int wv = threadIdx.x >> 6;
    int g = blockIdx.x * 4 + wv;
    int lane = threadIdx.x & 63;
    __shared__ float pooled_s[4][128];
    __shared__ float hid_s[4][128];
    if (g >= NG) return;

    int beg = gstart[g], end = gstart[g + 1];

    float m = -INFINITY;
    for (int i = beg + lane; i < end; i += 64) m = fmaxf(m, gate[i]);
#pragma unroll
    for (int o = 32; o; o >>= 1) m = fmaxf(m, __shfl_xor(m, o));
    float s = 0.f;
    for (int i = beg + lane; i < end; i += 64) s += expf(gate[i] - m);
#pragma unroll
    for (int o = 32; o; o >>= 1) s += __shfl_xor(s, o);
    float invs = (s > 0.f) ? 1.0f / s : 0.f;

    float ax = 0.f, ay = 0.f;
    const unsigned* hb = (const unsigned*)h;
    int i = beg;
    for (; i + 2 <= end; i += 2) {
        float w0 = expf(gate[i] - m) * invs;
        float w1 = expf(gate[i + 1] - m) * invs;
        unsigned v0 = hb[(size_t)i * 64 + lane];
        unsigned v1 = hb[(size_t)(i + 1) * 64 + lane];
        ax += w0 * lo16(v0) + w1 * lo16(v1);
        ay += w0 * hi16(v0) + w1 * hi16(v1);
    }
    for (; i < end; ++i) {
        float w = expf(gate[i] - m) * invs;
        unsigned v = hb[(size_t)i * 64 + lane];
        ax += w * lo16(v);
        ay += w * hi16(v);
    }
    pooled_s[wv][2 * lane] = ax;
    pooled_s[wv][2 * lane + 1] = ay;

    float h0 = l1b[lane], h1 = l1b[lane + 64];
    for (int k = 0; k < 128; ++k) {
        float pv = pooled_s[wv][k];
        h0 += pv * l1w[k * 128 + lane];
        h1 += pv * l1w[k * 128 + lane + 64];
    }
    hid_s[wv][lane] = fmaxf(h0, 0.f);
    hid_s[wv][lane + 64] = fmaxf(h1, 0.f);

    float o10 = 0.f;
    if (lane < NC) {
        o10 = l2b[lane];
        for (int k = 0; k < 128; ++k) o10 += hid_s[wv][k] * l2w[k * NC + lane];
    }
    float mm = -INFINITY;
#pragma unroll
    for (int j = 0; j < NC; ++j) mm = fmaxf(mm, __shfl(o10, j));
    float ss = 0.f;
#pragma unroll
    for (int j = 0; j < NC; ++j) ss += expf(__shfl(o10, j) - mm);
    float lse = mm + logf(ss);
    if (lane < NC) out[g * NC + lane] = o10 - lse;
}

extern "C" void kernel_launch(void* const* d_in, const int* in_sizes, int n_in,
                              void* d_out, int out_size, void* d_ws, size_t ws_size,
                              hipStream_t stream) {
    const float* x   = (const float*)d_in[0];
    const int* ei    = (const int*)d_in[1];
    const int* batch = (const int*)d_in[2];
    const float* w1l = (const float*)d_in[3];
    const float* b1  = (const float*)d_in[4];
    const float* w1r = (const float*)d_in[5];
    const float* w2l = (const float*)d_in[6];
    const float* b2  = (const float*)d_in[7];
    const float* w2r = (const float*)d_in[8];
    const float* w3l = (const float*)d_in[9];
    const float* b3  = (const float*)d_in[10];
    const float* w3r = (const float*)d_in[11];
    const float* gw  = (const float*)d_in[12];
    const float* gb  = (const float*)d_in[13];
    const float* l1w = (const float*)d_in[14];
    const float* l1b = (const float*)d_in[15];
    const float* l2w = (const float*)d_in[16];
    const float* l2b = (const float*)d_in[17];
    float* out = (float*)d_out;

    const int* src = ei;
    const int* dst = ei + N_EDGES;

    char* base = (char*)d_ws;
    size_t off = 0;
    auto carve = [&](size_t bytes) -> void* {
        void* r = base + off;
        off = (off + bytes + 255) & ~(size_t)255;
        return r;
    };
    int* rowptr         = (int*)carve((size_t)(N_NODES + 1) * 4);
    int* eidx           = (int*)carve((size_t)N_EDGES * 4);
    unsigned short* Bt  = (unsigned short*)carve((size_t)3 * 128 * 256 * 2);
    unsigned short* xb  = (unsigned short*)carve((size_t)N_NODES * NF * 2);
    unsigned short* mn  = (unsigned short*)carve((size_t)N_NODES * NF * 2);
    unsigned short* hA  = (unsigned short*)carve((size_t)N_NODES * NF * 2);
    unsigned short* hB  = (unsigned short*)carve((size_t)N_NODES * NF * 2);
    float* gate         = (float*)carve((size_t)N_NODES * 4);
    int* gstart         = (int*)carve(513 * 4);
    int* bcount         = (int*)carve((NBUCK + 1) * 4);
    int* bbase          = (int*)carve((NBUCK + 1) * 4);
    int* gcursor        = (int*)carve((NBUCK + 1) * 4);
    unsigned* brec      = (unsigned*)mn;  // alias: mn is dead until the first agg_kernel

    hipMemsetAsync(bcount, 0, (size_t)NBUCK * 4, stream);

    const int BUCK_B = (N_EDGES + EPB - 1) / EPB;  // 196
    bucket_count<<<BUCK_B, 256, 0, stream>>>(dst, bcount);
    bucket_scan<<<1, 512, 0, stream>>>(bcount, bbase, gcursor, rowptr);
    bucket_scatter<<<BUCK_B, 256, 0, stream>>>(src, dst, gcursor, brec);
    bucket_fill<<<NBUCK, 256, 0, stream>>>(brec, bbase, rowptr, eidx);

    build_bt<<<(3 * 128 * 256 + 255) / 256, 256, 0, stream>>>(w1l, w1r, w2l, w2r, w3l, w3r, Bt);
    cvt_kernel<<<(N_NODES * NF / 8 + 255) / 256, 256, 0, stream>>>(x, xb);

    const int AGG_B = (N_NODES + 3) / 4;          // 25000
    const int GEMM_B = (N_NODES + BM - 1) / BM;   // 782

    agg_kernel<<<AGG_B, 256, 0, stream>>>(xb, rowptr, eidx, mn);
    gemm_kernel<<<GEMM_B, 256, 0, stream>>>(mn, xb, Bt, b1, hA);
    agg_kernel<<<AGG_B, 256, 0, stream>>>(hA, rowptr, eidx, mn);
    gemm_kernel<<<GEMM_B, 256, 0, stream>>>(mn, hA, Bt + 32768, b2, hB);
    agg_kernel<<<AGG_B, 256, 0, stream>>>(hB, rowptr, eidx, mn);
    gemm_kernel<<<GEMM_B, 256, 0, stream>>>(mn, hB, Bt + 65536, b3, hA);

    gate_kernel<<<AGG_B, 256, 0, stream>>>(hA, gw, gb, gate);
    bounds_kernel<<<1, 1024, 0, stream>>>(batch, gstart);
    pool_mlp_kernel<<<(NG + 3) / 4, 256, 0, stream>>>(hA, gate, gstart, l1w, l1b, l2w, l2b, out);
}